// Round 6
// baseline (95.144 us; speedup 1.0000x reference)
//
#include <hip/hip_runtime.h>
#include <math.h>

#define N_NODES 4096
#define DIM     128
#define NPAIRS  32768
#define NEVENTS 4096
#define NTYPES  3
#define NREL    4
#define NNEIGH  16
#define WORDS   64   // 4096 bits / 64
#define MAXDEG  192  // deg ~ Binomial(4096, .02): mean 82, sd 9; P(>192) ~ 0

// Mask word layout (permuted): word w = ch*4+c (ch=chunk of 256 cols, c=component).
// Bit l of word w  <->  column (w>>2)*256 + l*4 + (w&3).

// Phase A block ranges
#define PA_MASK_END  (N_NODES / 4)                  // 1024 blocks: wave per row
#define PA_PROJ_END  (PA_MASK_END + N_NODES / 2)    // 2048 blocks: 2 nodes each
#define PA_HR_END    (PA_PROJ_END + N_NODES * NREL * DIM / 256) // 8192 blocks
#define PA_TOTAL     (PA_HR_END + 1)                // +1 block: sum_alpha

// ================= Phase A: mask+deg+nbrlist | proj | hr | sum_alpha =================
__global__ __launch_bounds__(256) void k_phaseA(const int* __restrict__ adj,
                                                unsigned long long* __restrict__ mask,
                                                float* __restrict__ degf,
                                                unsigned short* __restrict__ nbr,
                                                const float* __restrict__ x,
                                                const int* __restrict__ ntype,
                                                const float* __restrict__ Wp,
                                                float* __restrict__ proj,
                                                const int* __restrict__ nidx,
                                                float* __restrict__ h,
                                                const float* __restrict__ t_events,
                                                const float* __restrict__ theta_p,
                                                float* __restrict__ salpha) {
    __shared__ float smem[512];   // 2 KB, reused per branch
    int b = blockIdx.x;

    if (b < PA_MASK_END) {
        // ---- adjacency: wave per row; each lane ends owning word `lane` ----
        int wave = threadIdx.x >> 6;
        int lane = threadIdx.x & 63;
        int row  = b * 4 + wave;
        const int4* arow = (const int4*)(adj + (size_t)row * N_NODES);
        unsigned long long myw = 0ULL;
        #pragma unroll
        for (int ch = 0; ch < 16; ++ch) {
            int4 v = arow[ch * 64 + lane];
            unsigned long long b0 = __ballot(v.x != 0);
            unsigned long long b1 = __ballot(v.y != 0);
            unsigned long long b2 = __ballot(v.z != 0);
            unsigned long long b3 = __ballot(v.w != 0);
            if ((lane >> 2) == ch) {
                int c = lane & 3;
                myw = (c == 0) ? b0 : (c == 1) ? b1 : (c == 2) ? b2 : b3;
            }
        }
        mask[(size_t)row * WORDS + lane] = myw;
        // prefix-scan popcounts -> compaction offsets
        int pc = (int)__popcll(myw);
        int scan = pc;
        #pragma unroll
        for (int off = 1; off < 64; off <<= 1) {
            int nv = __shfl_up(scan, off);
            if (lane >= off) scan += nv;
        }
        int excl = scan - pc;
        if (lane == 63) degf[row] = (float)scan;
        unsigned short* nl = nbr + (size_t)row * MAXDEG;
        int jb = (lane >> 2) * 256 + (lane & 3);
        unsigned long long ww = myw;
        int o = excl;
        while (ww) {
            int bit = __ffsll(ww) - 1;
            nl[o++] = (unsigned short)(jb + bit * 4);
            ww &= ww - 1;
        }

    } else if (b < PA_PROJ_END) {
        // ---- proj[n] = x[n] @ W_proj[type[n]], 2 nodes per block ----
        int base = (b - PA_MASK_END) * 2;
        int g = threadIdx.x >> 7;
        int e = threadIdx.x & 127;
        int n = base + g;
        float* xs = smem;  // [2][128]
        xs[g * DIM + e] = x[(size_t)n * DIM + e];
        __syncthreads();
        int t = ntype[n];
        const float* W = Wp + (size_t)t * DIM * DIM + e;
        float acc = 0.f;
        #pragma unroll 8
        for (int d = 0; d < DIM; ++d)
            acc += xs[g * DIM + d] * W[(size_t)d * DIM];
        proj[(size_t)n * DIM + e] = acc;

    } else if (b < PA_HR_END) {
        // ---- h[n][r][d] = mean_k x[nidx[n][r][k]][d] ----
        int tid = (b - PA_PROJ_END) * 256 + threadIdx.x;
        int d  = tid & (DIM - 1);
        int nr = tid >> 7;
        const int4* idx4 = (const int4*)(nidx + (size_t)nr * NNEIGH);
        int4 i0 = idx4[0], i1 = idx4[1], i2 = idx4[2], i3 = idx4[3];
        float s = 0.f;
        s += x[(size_t)i0.x * DIM + d]; s += x[(size_t)i0.y * DIM + d];
        s += x[(size_t)i0.z * DIM + d]; s += x[(size_t)i0.w * DIM + d];
        s += x[(size_t)i1.x * DIM + d]; s += x[(size_t)i1.y * DIM + d];
        s += x[(size_t)i1.z * DIM + d]; s += x[(size_t)i1.w * DIM + d];
        s += x[(size_t)i2.x * DIM + d]; s += x[(size_t)i2.y * DIM + d];
        s += x[(size_t)i2.z * DIM + d]; s += x[(size_t)i2.w * DIM + d];
        s += x[(size_t)i3.x * DIM + d]; s += x[(size_t)i3.y * DIM + d];
        s += x[(size_t)i3.z * DIM + d]; s += x[(size_t)i3.w * DIM + d];
        h[tid] = s * (1.0f / 16.0f);

    } else {
        // ---- sum_alpha ----
        float th = theta_p[0];
        float acc = 0.f;
        for (int i = threadIdx.x; i < NEVENTS; i += 256)
            acc += expf(-th * (1.0f - t_events[i]));
        smem[threadIdx.x] = acc;
        __syncthreads();
        for (int s = 128; s > 0; s >>= 1) {
            if (threadIdx.x < s) smem[threadIdx.x] += smem[threadIdx.x + s];
            __syncthreads();
        }
        if (threadIdx.x == 0) salpha[0] = smem[0];
    }
}

// ================= Phase B: clust (wave/node, list-driven) | eps_mm (8 nodes/blk) =================
__global__ __launch_bounds__(256) void k_phaseB(const unsigned long long* __restrict__ mask,
                                                const float* __restrict__ degf,
                                                const unsigned short* __restrict__ nbr,
                                                float* __restrict__ C,
                                                const float* __restrict__ h,
                                                const float* __restrict__ Wb,
                                                const float* __restrict__ bb,
                                                float* __restrict__ eps) {
    __shared__ float smem[6144];  // 24 KB: eps: hs[8][512] + part[2][8][128]
    int b = blockIdx.x;

    if (b < N_NODES / 4) {
        // ---- tri: wave per node; neighbor ids from registers via shfl; unroll 4 ----
        int wave = threadIdx.x >> 6;
        int lane = threadIdx.x & 63;
        int node = b * 4 + wave;
        unsigned long long my = mask[(size_t)node * WORDS + lane];
        int dg = (int)degf[node];
        const unsigned short* nl = nbr + (size_t)node * MAXDEG;
        int i0 = nl[lane], i1 = nl[64 + lane], i2 = nl[128 + lane];
        unsigned int acc = 0;
        #pragma unroll 4
        for (int it = 0; it < dg; ++it) {
            int sel = (it < 64) ? i0 : (it < 128) ? i1 : i2;
            int j = __shfl(sel, it & 63);
            acc += __popcll(my & mask[(size_t)j * WORDS + lane]);
        }
        for (int off = 32; off > 0; off >>= 1) acc += __shfl_xor(acc, off);
        if (lane == 0) {
            float dgF = (float)dg;
            float denom = dgF * (dgF - 1.0f);
            if (denom == 0.0f) denom = 1e-6f;
            C[node] = 2.0f * (float)acc / denom;
        }

    } else {
        // ---- eps: 8 nodes/block, K split across halves, float4 LDS reads ----
        int base = (b - N_NODES / 4) * 8;
        int e = threadIdx.x & 127;
        int g = threadIdx.x >> 7;        // k-half
        float* hs = smem;                // [8][512]
        float* part = smem + 4096;       // [2][8][128]
        const float4* hsrc = (const float4*)(h + (size_t)base * NREL * DIM);
        float4* hs4 = (float4*)hs;
        #pragma unroll
        for (int i = 0; i < 4; ++i) hs4[threadIdx.x + i * 256] = hsrc[threadIdx.x + i * 256];
        __syncthreads();
        const float* W = Wb + (size_t)(g * 256) * DIM + e;
        const float4* h4 = (const float4*)hs;
        int kq = g * 64;                 // k0/4
        float a[8] = {0.f, 0.f, 0.f, 0.f, 0.f, 0.f, 0.f, 0.f};
        #pragma unroll 2
        for (int kg = 0; kg < 64; ++kg) {
            float w0 = W[(size_t)(4 * kg + 0) * DIM];
            float w1 = W[(size_t)(4 * kg + 1) * DIM];
            float w2 = W[(size_t)(4 * kg + 2) * DIM];
            float w3 = W[(size_t)(4 * kg + 3) * DIM];
            #pragma unroll
            for (int m = 0; m < 8; ++m) {
                float4 hv = h4[m * 128 + kq + kg];
                a[m] += hv.x * w0 + hv.y * w1 + hv.z * w2 + hv.w * w3;
            }
        }
        #pragma unroll
        for (int m = 0; m < 8; ++m) part[(g * 8 + m) * 128 + e] = a[m];
        __syncthreads();
        if (g == 0) {
            float bsum = bb[e] + bb[DIM + e] + bb[2 * DIM + e] + bb[3 * DIM + e];
            #pragma unroll
            for (int m = 0; m < 8; ++m) {
                float v = (part[m * 128 + e] + part[(8 + m) * 128 + e] + bsum) * 0.25f;
                eps[(size_t)(base + m) * DIM + e] = 1.0f / (1.0f + expf(-v));
            }
        }
    }
}

// ================= Phase C: per-pair fused epilogue (one wave per pair) =================
__global__ __launch_bounds__(256) void k_pairs(const int* __restrict__ pairs,
                                               const unsigned long long* __restrict__ mask,
                                               const float* __restrict__ C,
                                               const float* __restrict__ proj,
                                               const float* __restrict__ eps,
                                               const float* __restrict__ x,
                                               const float* __restrict__ salpha_p,
                                               const float* __restrict__ q1p,
                                               const float* __restrict__ q2p,
                                               float* __restrict__ out) {
    int wave = threadIdx.x >> 6;
    int lane = threadIdx.x & 63;
    int p = blockIdx.x * 4 + wave;
    int pm = pairs[p * 2];
    int pn = pairs[p * 2 + 1];

    unsigned long long cw = mask[(size_t)pm * WORDS + lane] & mask[(size_t)pn * WORDS + lane];
    float csum = 0.f;
    int jbase = (lane >> 2) * 256 + (lane & 3);
    while (cw) {
        int bit = __ffsll(cw) - 1;
        csum += C[jbase + bit * 4];
        cw &= cw - 1;
    }

    const float2* Am = (const float2*)(proj + (size_t)pm * DIM);
    const float2* An = (const float2*)(proj + (size_t)pn * DIM);
    const float2* Xm = (const float2*)(x    + (size_t)pm * DIM);
    const float2* Xn = (const float2*)(x    + (size_t)pn * DIM);
    const float2* Em = (const float2*)(eps  + (size_t)pm * DIM);
    const float2* En = (const float2*)(eps  + (size_t)pn * DIM);
    float2 am = Am[lane], an = An[lane];
    float2 xm = Xm[lane], xn = Xn[lane];
    float2 em = Em[lane], en = En[lane];

    float dpx = am.x - an.x, dpy = am.y - an.y;
    float s1 = dpx * dpx + dpy * dpy;
    float dxx = xm.x - xn.x, dxy = xm.y - xn.y;
    float s2 = dxx * dxx + dxy * dxy;
    float s3 = em.x * en.x + em.y * en.y;

    for (int off = 32; off > 0; off >>= 1) {
        s1 += __shfl_xor(s1, off);
        s2 += __shfl_xor(s2, off);
        s3 += __shfl_xor(s3, off);
        csum += __shfl_xor(csum, off);
    }
    if (lane == 0) {
        float lhist  = -sqrtf(s1) + salpha_p[0];
        float ltri   = csum * (-s2);
        float lneigh = s3 * (1.0f / 128.0f);
        float lam = expf(lhist + ltri + lneigh);
        float z = q1p[0] * lam + q2p[0];
        out[p] = 1.0f / (1.0f + expf(-z));
    }
}

extern "C" void kernel_launch(void* const* d_in, const int* in_sizes, int n_in,
                              void* d_out, int out_size, void* d_ws, size_t ws_size,
                              hipStream_t stream) {
    const int*   pairs    = (const int*)d_in[0];
    const int*   adj      = (const int*)d_in[1];
    const int*   nidx     = (const int*)d_in[2];
    const int*   ntype    = (const int*)d_in[3];
    const float* t_events = (const float*)d_in[4];
    const float* x        = (const float*)d_in[5];
    const float* Wp       = (const float*)d_in[6];
    const float* Wb       = (const float*)d_in[7];
    const float* bb       = (const float*)d_in[8];
    const float* theta    = (const float*)d_in[9];
    const float* q1       = (const float*)d_in[10];
    const float* q2       = (const float*)d_in[11];
    float* out = (float*)d_out;

    char* ws = (char*)d_ws;
    unsigned long long* mask = (unsigned long long*)(ws + 0);      // 2 MB
    float* deg    = (float*)(ws + 2097152);                        // 16 KB
    float* C      = (float*)(ws + 2113536);                        // 16 KB
    float* proj   = (float*)(ws + 2129920);                        // 2 MB
    float* eps    = (float*)(ws + 4227072);                        // 2 MB
    float* salpha = (float*)(ws + 6324224);                        // 4 B
    float* h      = (float*)(ws + 6324352);                        // 8 MB
    unsigned short* nbr = (unsigned short*)(ws + 14712960);        // 1.5 MB

    hipLaunchKernelGGL(k_phaseA, dim3(PA_TOTAL),              dim3(256), 0, stream,
                       adj, mask, deg, nbr, x, ntype, Wp, proj, nidx, h, t_events, theta, salpha);
    hipLaunchKernelGGL(k_phaseB, dim3(N_NODES / 4 + N_NODES / 8), dim3(256), 0, stream,
                       mask, deg, nbr, C, h, Wb, bb, eps);
    hipLaunchKernelGGL(k_pairs,  dim3(NPAIRS / 4),            dim3(256), 0, stream,
                       pairs, mask, C, proj, eps, x, salpha, q1, q2, out);
}

// Round 7
// 87.503 us; speedup vs baseline: 1.0873x; 1.0873x over previous
//
#include <hip/hip_runtime.h>
#include <math.h>

#define N_NODES 4096
#define DIM     128
#define NPAIRS  32768
#define NEVENTS 4096
#define NTYPES  3
#define NREL    4
#define NNEIGH  16
#define WORDS   64   // 4096 bits / 64
#define MAXDEG  192  // deg ~ Binomial(4096, .02): mean 82, sd 9; P(>192) ~ 0

// Mask word layout (permuted): word w = ch*4+c (ch=chunk of 256 cols, c=component).
// Bit l of word w  <->  column (w>>2)*256 + l*4 + (w&3).

// Phase A block ranges
#define PA_MASK_END  (N_NODES / 4)                  // 1024 blocks: wave per row
#define PA_PROJ_END  (PA_MASK_END + N_NODES / 2)    // 2048 blocks: 2 nodes each
#define PA_HR_END    (PA_PROJ_END + N_NODES * NREL * DIM / 256) // 8192 blocks
#define PA_TOTAL     (PA_HR_END + 1)                // +1 block: sum_alpha

// ================= Phase A: mask+deg+nbrlist | proj | hr | sum_alpha =================
__global__ __launch_bounds__(256) void k_phaseA(const int* __restrict__ adj,
                                                unsigned long long* __restrict__ mask,
                                                float* __restrict__ degf,
                                                unsigned short* __restrict__ nbr,
                                                const float* __restrict__ x,
                                                const int* __restrict__ ntype,
                                                const float* __restrict__ Wp,
                                                float* __restrict__ proj,
                                                const int* __restrict__ nidx,
                                                float* __restrict__ h,
                                                const float* __restrict__ t_events,
                                                const float* __restrict__ theta_p,
                                                float* __restrict__ salpha) {
    __shared__ float smem[512];   // 2 KB, reused per branch
    int b = blockIdx.x;

    if (b < PA_MASK_END) {
        // ---- adjacency: wave per row; each lane ends owning word `lane` ----
        int wave = threadIdx.x >> 6;
        int lane = threadIdx.x & 63;
        int row  = b * 4 + wave;
        const int4* arow = (const int4*)(adj + (size_t)row * N_NODES);
        unsigned long long myw = 0ULL;
        #pragma unroll
        for (int ch = 0; ch < 16; ++ch) {
            int4 v = arow[ch * 64 + lane];
            unsigned long long b0 = __ballot(v.x != 0);
            unsigned long long b1 = __ballot(v.y != 0);
            unsigned long long b2 = __ballot(v.z != 0);
            unsigned long long b3 = __ballot(v.w != 0);
            if ((lane >> 2) == ch) {
                int c = lane & 3;
                myw = (c == 0) ? b0 : (c == 1) ? b1 : (c == 2) ? b2 : b3;
            }
        }
        mask[(size_t)row * WORDS + lane] = myw;
        // prefix-scan popcounts -> compaction offsets
        int pc = (int)__popcll(myw);
        int scan = pc;
        #pragma unroll
        for (int off = 1; off < 64; off <<= 1) {
            int nv = __shfl_up(scan, off);
            if (lane >= off) scan += nv;
        }
        int excl = scan - pc;
        if (lane == 63) degf[row] = (float)scan;
        unsigned short* nl = nbr + (size_t)row * MAXDEG;
        int jb = (lane >> 2) * 256 + (lane & 3);
        unsigned long long ww = myw;
        int o = excl;
        while (ww) {
            int bit = __ffsll(ww) - 1;
            nl[o++] = (unsigned short)(jb + bit * 4);
            ww &= ww - 1;
        }

    } else if (b < PA_PROJ_END) {
        // ---- proj[n] = x[n] @ W_proj[type[n]], 2 nodes per block ----
        int base = (b - PA_MASK_END) * 2;
        int g = threadIdx.x >> 7;
        int e = threadIdx.x & 127;
        int n = base + g;
        float* xs = smem;  // [2][128]
        xs[g * DIM + e] = x[(size_t)n * DIM + e];
        __syncthreads();
        int t = ntype[n];
        const float* W = Wp + (size_t)t * DIM * DIM + e;
        float acc = 0.f;
        #pragma unroll 8
        for (int d = 0; d < DIM; ++d)
            acc += xs[g * DIM + d] * W[(size_t)d * DIM];
        proj[(size_t)n * DIM + e] = acc;

    } else if (b < PA_HR_END) {
        // ---- h[n][r][d] = mean_k x[nidx[n][r][k]][d] ----
        int tid = (b - PA_PROJ_END) * 256 + threadIdx.x;
        int d  = tid & (DIM - 1);
        int nr = tid >> 7;
        const int4* idx4 = (const int4*)(nidx + (size_t)nr * NNEIGH);
        int4 i0 = idx4[0], i1 = idx4[1], i2 = idx4[2], i3 = idx4[3];
        float s = 0.f;
        s += x[(size_t)i0.x * DIM + d]; s += x[(size_t)i0.y * DIM + d];
        s += x[(size_t)i0.z * DIM + d]; s += x[(size_t)i0.w * DIM + d];
        s += x[(size_t)i1.x * DIM + d]; s += x[(size_t)i1.y * DIM + d];
        s += x[(size_t)i1.z * DIM + d]; s += x[(size_t)i1.w * DIM + d];
        s += x[(size_t)i2.x * DIM + d]; s += x[(size_t)i2.y * DIM + d];
        s += x[(size_t)i2.z * DIM + d]; s += x[(size_t)i2.w * DIM + d];
        s += x[(size_t)i3.x * DIM + d]; s += x[(size_t)i3.y * DIM + d];
        s += x[(size_t)i3.z * DIM + d]; s += x[(size_t)i3.w * DIM + d];
        h[tid] = s * (1.0f / 16.0f);

    } else {
        // ---- sum_alpha ----
        float th = theta_p[0];
        float acc = 0.f;
        for (int i = threadIdx.x; i < NEVENTS; i += 256)
            acc += expf(-th * (1.0f - t_events[i]));
        smem[threadIdx.x] = acc;
        __syncthreads();
        for (int s = 128; s > 0; s >>= 1) {
            if (threadIdx.x < s) smem[threadIdx.x] += smem[threadIdx.x + s];
            __syncthreads();
        }
        if (threadIdx.x == 0) salpha[0] = smem[0];
    }
}

// ================= Phase B: clust (block/node, strided wave slices) | eps_mm (4 nodes/blk) =================
__global__ __launch_bounds__(256) void k_phaseB(const unsigned long long* __restrict__ mask,
                                                const float* __restrict__ degf,
                                                const unsigned short* __restrict__ nbr,
                                                float* __restrict__ C,
                                                const float* __restrict__ h,
                                                const float* __restrict__ Wb,
                                                const float* __restrict__ bb,
                                                float* __restrict__ eps) {
    __shared__ float smem[3072];  // 12 KB: eps: hs[4][512] + part[2][4][128]; clust: 4 uints
    int b = blockIdx.x;

    if (b < N_NODES) {
        // ---- tri: block per node; wave w handles neighbors it = w + 4t from list ----
        int wave = threadIdx.x >> 6;
        int lane = threadIdx.x & 63;
        int node = b;
        unsigned long long my = mask[(size_t)node * WORDS + lane];
        int dg = (int)degf[node];
        const unsigned short* nl = nbr + (size_t)node * MAXDEG;
        // lane t preloads the neighbor id for iteration t of this wave
        int pidx = wave + 4 * lane;
        int pre = (lane < 48) ? (int)nl[pidx] : 0;
        int nit = (dg - wave + 3) >> 2;   // #t with wave+4t < dg (0 if dg<=wave)
        if (nit < 0) nit = 0;
        unsigned int acc = 0;
        #pragma unroll 4
        for (int t = 0; t < nit; ++t) {
            int j = __shfl(pre, t);
            acc += __popcll(my & mask[(size_t)j * WORDS + lane]);
        }
        for (int off = 32; off > 0; off >>= 1) acc += __shfl_xor(acc, off);
        unsigned int* wacc = (unsigned int*)smem;
        if (lane == 0) wacc[wave] = acc;
        __syncthreads();
        if (threadIdx.x == 0) {
            float tri = (float)(wacc[0] + wacc[1] + wacc[2] + wacc[3]);
            float dgF = (float)dg;
            float denom = dgF * (dgF - 1.0f);
            if (denom == 0.0f) denom = 1e-6f;
            C[node] = 2.0f * tri / denom;
        }

    } else {
        // ---- eps: 4 nodes/block, K split across wave-halves (g = tid>>7) ----
        int base = (b - N_NODES) * 4;
        int e = threadIdx.x & 127;
        int g = threadIdx.x >> 7;        // k-half
        float* hs = smem;                // [4][512]
        float* part = smem + 2048;       // [2][4][128]
        const float4* hsrc = (const float4*)(h + (size_t)base * NREL * DIM);
        float4* hs4 = (float4*)hs;
        for (int i = threadIdx.x; i < 512; i += 256) hs4[i] = hsrc[i];
        __syncthreads();
        const float* W = Wb + (size_t)(g * 256) * DIM + e;
        const float4* h4 = (const float4*)hs;
        int kq = g * 64;                 // float4 index base
        float a0 = 0.f, a1 = 0.f, a2 = 0.f, a3 = 0.f;
        #pragma unroll 4
        for (int kg = 0; kg < 64; ++kg) {
            float w0 = W[(size_t)(4 * kg + 0) * DIM];
            float w1 = W[(size_t)(4 * kg + 1) * DIM];
            float w2 = W[(size_t)(4 * kg + 2) * DIM];
            float w3 = W[(size_t)(4 * kg + 3) * DIM];
            float4 h0 = h4[0 * 128 + kq + kg];
            float4 h1 = h4[1 * 128 + kq + kg];
            float4 h2 = h4[2 * 128 + kq + kg];
            float4 h3 = h4[3 * 128 + kq + kg];
            a0 += h0.x * w0 + h0.y * w1 + h0.z * w2 + h0.w * w3;
            a1 += h1.x * w0 + h1.y * w1 + h1.z * w2 + h1.w * w3;
            a2 += h2.x * w0 + h2.y * w1 + h2.z * w2 + h2.w * w3;
            a3 += h3.x * w0 + h3.y * w1 + h3.z * w2 + h3.w * w3;
        }
        part[(g * 4 + 0) * 128 + e] = a0;
        part[(g * 4 + 1) * 128 + e] = a1;
        part[(g * 4 + 2) * 128 + e] = a2;
        part[(g * 4 + 3) * 128 + e] = a3;
        __syncthreads();
        if (g == 0) {
            float bsum = bb[e] + bb[DIM + e] + bb[2 * DIM + e] + bb[3 * DIM + e];
            #pragma unroll
            for (int m = 0; m < 4; ++m) {
                float v = (part[m * 128 + e] + part[(4 + m) * 128 + e] + bsum) * 0.25f;
                eps[(size_t)(base + m) * DIM + e] = 1.0f / (1.0f + expf(-v));
            }
        }
    }
}

// ================= Phase C: per-pair fused epilogue (one wave per pair) =================
__global__ __launch_bounds__(256) void k_pairs(const int* __restrict__ pairs,
                                               const unsigned long long* __restrict__ mask,
                                               const float* __restrict__ C,
                                               const float* __restrict__ proj,
                                               const float* __restrict__ eps,
                                               const float* __restrict__ x,
                                               const float* __restrict__ salpha_p,
                                               const float* __restrict__ q1p,
                                               const float* __restrict__ q2p,
                                               float* __restrict__ out) {
    int wave = threadIdx.x >> 6;
    int lane = threadIdx.x & 63;
    int p = blockIdx.x * 4 + wave;
    int pm = pairs[p * 2];
    int pn = pairs[p * 2 + 1];

    unsigned long long cw = mask[(size_t)pm * WORDS + lane] & mask[(size_t)pn * WORDS + lane];
    float csum = 0.f;
    int jbase = (lane >> 2) * 256 + (lane & 3);
    while (cw) {
        int bit = __ffsll(cw) - 1;
        csum += C[jbase + bit * 4];
        cw &= cw - 1;
    }

    const float2* Am = (const float2*)(proj + (size_t)pm * DIM);
    const float2* An = (const float2*)(proj + (size_t)pn * DIM);
    const float2* Xm = (const float2*)(x    + (size_t)pm * DIM);
    const float2* Xn = (const float2*)(x    + (size_t)pn * DIM);
    const float2* Em = (const float2*)(eps  + (size_t)pm * DIM);
    const float2* En = (const float2*)(eps  + (size_t)pn * DIM);
    float2 am = Am[lane], an = An[lane];
    float2 xm = Xm[lane], xn = Xn[lane];
    float2 em = Em[lane], en = En[lane];

    float dpx = am.x - an.x, dpy = am.y - an.y;
    float s1 = dpx * dpx + dpy * dpy;
    float dxx = xm.x - xn.x, dxy = xm.y - xn.y;
    float s2 = dxx * dxx + dxy * dxy;
    float s3 = em.x * en.x + em.y * en.y;

    for (int off = 32; off > 0; off >>= 1) {
        s1 += __shfl_xor(s1, off);
        s2 += __shfl_xor(s2, off);
        s3 += __shfl_xor(s3, off);
        csum += __shfl_xor(csum, off);
    }
    if (lane == 0) {
        float lhist  = -sqrtf(s1) + salpha_p[0];
        float ltri   = csum * (-s2);
        float lneigh = s3 * (1.0f / 128.0f);
        float lam = expf(lhist + ltri + lneigh);
        float z = q1p[0] * lam + q2p[0];
        out[p] = 1.0f / (1.0f + expf(-z));
    }
}

extern "C" void kernel_launch(void* const* d_in, const int* in_sizes, int n_in,
                              void* d_out, int out_size, void* d_ws, size_t ws_size,
                              hipStream_t stream) {
    const int*   pairs    = (const int*)d_in[0];
    const int*   adj      = (const int*)d_in[1];
    const int*   nidx     = (const int*)d_in[2];
    const int*   ntype    = (const int*)d_in[3];
    const float* t_events = (const float*)d_in[4];
    const float* x        = (const float*)d_in[5];
    const float* Wp       = (const float*)d_in[6];
    const float* Wb       = (const float*)d_in[7];
    const float* bb       = (const float*)d_in[8];
    const float* theta    = (const float*)d_in[9];
    const float* q1       = (const float*)d_in[10];
    const float* q2       = (const float*)d_in[11];
    float* out = (float*)d_out;

    char* ws = (char*)d_ws;
    unsigned long long* mask = (unsigned long long*)(ws + 0);      // 2 MB
    float* deg    = (float*)(ws + 2097152);                        // 16 KB
    float* C      = (float*)(ws + 2113536);                        // 16 KB
    float* proj   = (float*)(ws + 2129920);                        // 2 MB
    float* eps    = (float*)(ws + 4227072);                        // 2 MB
    float* salpha = (float*)(ws + 6324224);                        // 4 B
    float* h      = (float*)(ws + 6324352);                        // 8 MB
    unsigned short* nbr = (unsigned short*)(ws + 14712960);        // 1.5 MB

    hipLaunchKernelGGL(k_phaseA, dim3(PA_TOTAL),              dim3(256), 0, stream,
                       adj, mask, deg, nbr, x, ntype, Wp, proj, nidx, h, t_events, theta, salpha);
    hipLaunchKernelGGL(k_phaseB, dim3(N_NODES + N_NODES / 4), dim3(256), 0, stream,
                       mask, deg, nbr, C, h, Wb, bb, eps);
    hipLaunchKernelGGL(k_pairs,  dim3(NPAIRS / 4),            dim3(256), 0, stream,
                       pairs, mask, C, proj, eps, x, salpha, q1, q2, out);
}

// Round 8
// 87.298 us; speedup vs baseline: 1.0899x; 1.0024x over previous
//
#include <hip/hip_runtime.h>
#include <math.h>

#define N_NODES 4096
#define DIM     128
#define NPAIRS  32768
#define NEVENTS 4096
#define NTYPES  3
#define NREL    4
#define NNEIGH  16
#define WORDS   64   // 4096 bits / 64
#define MAXDEG  192  // deg ~ Binomial(4096, .02): mean 82, sd 9; P(>192) ~ 0

// Mask word layout (permuted): word w = ch*4+c (ch=chunk of 256 cols, c=component).
// Bit l of word w  <->  column (w>>2)*256 + l*4 + (w&3).

// Phase A block ranges
#define PA_MASK_END  (N_NODES / 4)                  // 1024 blocks: wave per row
#define PA_PROJ_END  (PA_MASK_END + N_NODES / 2)    // 2048 blocks: 2 nodes each
#define PA_HR_END    (PA_PROJ_END + N_NODES * NREL * DIM / 256) // 8192 blocks
#define PA_TOTAL     (PA_HR_END + 1)                // +1 block: sum_alpha

// Phase B: 5120 blocks; b%5==0 -> eps (1024 blocks), else clust (4096 blocks)
#define PB_TOTAL     (N_NODES + N_NODES / 4)

// ================= Phase A: mask+deg+nbrlist | proj | hr | sum_alpha =================
__global__ __launch_bounds__(256) void k_phaseA(const int* __restrict__ adj,
                                                unsigned long long* __restrict__ mask,
                                                float* __restrict__ degf,
                                                unsigned short* __restrict__ nbr,
                                                const float* __restrict__ x,
                                                const int* __restrict__ ntype,
                                                const float* __restrict__ Wp,
                                                float* __restrict__ proj,
                                                const int* __restrict__ nidx,
                                                float* __restrict__ h,
                                                const float* __restrict__ t_events,
                                                const float* __restrict__ theta_p,
                                                float* __restrict__ salpha) {
    __shared__ float smem[512];   // 2 KB, reused per branch
    int b = blockIdx.x;

    if (b < PA_MASK_END) {
        // ---- adjacency: wave per row; each lane ends owning word `lane` ----
        int wave = threadIdx.x >> 6;
        int lane = threadIdx.x & 63;
        int row  = b * 4 + wave;
        const int4* arow = (const int4*)(adj + (size_t)row * N_NODES);
        unsigned long long myw = 0ULL;
        #pragma unroll
        for (int ch = 0; ch < 16; ++ch) {
            int4 v = arow[ch * 64 + lane];
            unsigned long long b0 = __ballot(v.x != 0);
            unsigned long long b1 = __ballot(v.y != 0);
            unsigned long long b2 = __ballot(v.z != 0);
            unsigned long long b3 = __ballot(v.w != 0);
            if ((lane >> 2) == ch) {
                int c = lane & 3;
                myw = (c == 0) ? b0 : (c == 1) ? b1 : (c == 2) ? b2 : b3;
            }
        }
        mask[(size_t)row * WORDS + lane] = myw;
        // prefix-scan popcounts -> compaction offsets
        int pc = (int)__popcll(myw);
        int scan = pc;
        #pragma unroll
        for (int off = 1; off < 64; off <<= 1) {
            int nv = __shfl_up(scan, off);
            if (lane >= off) scan += nv;
        }
        int excl = scan - pc;
        if (lane == 63) degf[row] = (float)scan;
        unsigned short* nl = nbr + (size_t)row * MAXDEG;
        int jb = (lane >> 2) * 256 + (lane & 3);
        unsigned long long ww = myw;
        int o = excl;
        while (ww) {
            int bit = __ffsll(ww) - 1;
            nl[o++] = (unsigned short)(jb + bit * 4);
            ww &= ww - 1;
        }

    } else if (b < PA_PROJ_END) {
        // ---- proj[n] = x[n] @ W_proj[type[n]], 2 nodes per block ----
        int base = (b - PA_MASK_END) * 2;
        int g = threadIdx.x >> 7;
        int e = threadIdx.x & 127;
        int n = base + g;
        float* xs = smem;  // [2][128]
        xs[g * DIM + e] = x[(size_t)n * DIM + e];
        __syncthreads();
        int t = ntype[n];
        const float* W = Wp + (size_t)t * DIM * DIM + e;
        float acc = 0.f;
        #pragma unroll 8
        for (int d = 0; d < DIM; ++d)
            acc += xs[g * DIM + d] * W[(size_t)d * DIM];
        proj[(size_t)n * DIM + e] = acc;

    } else if (b < PA_HR_END) {
        // ---- h[n][r][d] = mean_k x[nidx[n][r][k]][d] ----
        int tid = (b - PA_PROJ_END) * 256 + threadIdx.x;
        int d  = tid & (DIM - 1);
        int nr = tid >> 7;
        const int4* idx4 = (const int4*)(nidx + (size_t)nr * NNEIGH);
        int4 i0 = idx4[0], i1 = idx4[1], i2 = idx4[2], i3 = idx4[3];
        float s = 0.f;
        s += x[(size_t)i0.x * DIM + d]; s += x[(size_t)i0.y * DIM + d];
        s += x[(size_t)i0.z * DIM + d]; s += x[(size_t)i0.w * DIM + d];
        s += x[(size_t)i1.x * DIM + d]; s += x[(size_t)i1.y * DIM + d];
        s += x[(size_t)i1.z * DIM + d]; s += x[(size_t)i1.w * DIM + d];
        s += x[(size_t)i2.x * DIM + d]; s += x[(size_t)i2.y * DIM + d];
        s += x[(size_t)i2.z * DIM + d]; s += x[(size_t)i2.w * DIM + d];
        s += x[(size_t)i3.x * DIM + d]; s += x[(size_t)i3.y * DIM + d];
        s += x[(size_t)i3.z * DIM + d]; s += x[(size_t)i3.w * DIM + d];
        h[tid] = s * (1.0f / 16.0f);

    } else {
        // ---- sum_alpha ----
        float th = theta_p[0];
        float acc = 0.f;
        for (int i = threadIdx.x; i < NEVENTS; i += 256)
            acc += expf(-th * (1.0f - t_events[i]));
        smem[threadIdx.x] = acc;
        __syncthreads();
        for (int s = 128; s > 0; s >>= 1) {
            if (threadIdx.x < s) smem[threadIdx.x] += smem[threadIdx.x + s];
            __syncthreads();
        }
        if (threadIdx.x == 0) salpha[0] = smem[0];
    }
}

// ================= Phase B: clust | eps, INTERLEAVED block roles =================
__global__ __launch_bounds__(256) void k_phaseB(const unsigned long long* __restrict__ mask,
                                                const float* __restrict__ degf,
                                                const unsigned short* __restrict__ nbr,
                                                float* __restrict__ C,
                                                const float* __restrict__ h,
                                                const float* __restrict__ Wb,
                                                const float* __restrict__ bb,
                                                float* __restrict__ eps) {
    __shared__ float smem[3072];  // 12 KB: eps: hs[4][512] + part[2][4][128]; clust: 4 uints
    int b = blockIdx.x;
    int bq = b / 5;

    if (b % 5 != 0) {
        // ---- tri: block per node; wave w handles neighbors it = w + 4t from list ----
        int node = b - bq - 1;     // bijection onto [0, 4096)
        int wave = threadIdx.x >> 6;
        int lane = threadIdx.x & 63;
        unsigned long long my = mask[(size_t)node * WORDS + lane];
        int dg = (int)degf[node];
        const unsigned short* nl = nbr + (size_t)node * MAXDEG;
        // lane t preloads the neighbor id for iteration t of this wave
        int pidx = wave + 4 * lane;
        int pre = (lane < 48) ? (int)nl[pidx] : 0;
        int nit = (dg - wave + 3) >> 2;   // #t with wave+4t < dg (0 if dg<=wave)
        if (nit < 0) nit = 0;
        unsigned int acc = 0;
        #pragma unroll 4
        for (int t = 0; t < nit; ++t) {
            int j = __shfl(pre, t);
            acc += __popcll(my & mask[(size_t)j * WORDS + lane]);
        }
        for (int off = 32; off > 0; off >>= 1) acc += __shfl_xor(acc, off);
        unsigned int* wacc = (unsigned int*)smem;
        if (lane == 0) wacc[wave] = acc;
        __syncthreads();
        if (threadIdx.x == 0) {
            float tri = (float)(wacc[0] + wacc[1] + wacc[2] + wacc[3]);
            float dgF = (float)dg;
            float denom = dgF * (dgF - 1.0f);
            if (denom == 0.0f) denom = 1e-6f;
            C[node] = 2.0f * tri / denom;
        }

    } else {
        // ---- eps: 4 nodes/block, K split across wave-halves (g = tid>>7) ----
        int base = bq * 4;
        int e = threadIdx.x & 127;
        int g = threadIdx.x >> 7;        // k-half
        float* hs = smem;                // [4][512]
        float* part = smem + 2048;       // [2][4][128]
        const float4* hsrc = (const float4*)(h + (size_t)base * NREL * DIM);
        float4* hs4 = (float4*)hs;
        for (int i = threadIdx.x; i < 512; i += 256) hs4[i] = hsrc[i];
        __syncthreads();
        const float* W = Wb + (size_t)(g * 256) * DIM + e;
        const float4* h4 = (const float4*)hs;
        int kq = g * 64;                 // float4 index base
        float a0 = 0.f, a1 = 0.f, a2 = 0.f, a3 = 0.f;
        #pragma unroll 4
        for (int kg = 0; kg < 64; ++kg) {
            float w0 = W[(size_t)(4 * kg + 0) * DIM];
            float w1 = W[(size_t)(4 * kg + 1) * DIM];
            float w2 = W[(size_t)(4 * kg + 2) * DIM];
            float w3 = W[(size_t)(4 * kg + 3) * DIM];
            float4 h0 = h4[0 * 128 + kq + kg];
            float4 h1 = h4[1 * 128 + kq + kg];
            float4 h2 = h4[2 * 128 + kq + kg];
            float4 h3 = h4[3 * 128 + kq + kg];
            a0 += h0.x * w0 + h0.y * w1 + h0.z * w2 + h0.w * w3;
            a1 += h1.x * w0 + h1.y * w1 + h1.z * w2 + h1.w * w3;
            a2 += h2.x * w0 + h2.y * w1 + h2.z * w2 + h2.w * w3;
            a3 += h3.x * w0 + h3.y * w1 + h3.z * w2 + h3.w * w3;
        }
        part[(g * 4 + 0) * 128 + e] = a0;
        part[(g * 4 + 1) * 128 + e] = a1;
        part[(g * 4 + 2) * 128 + e] = a2;
        part[(g * 4 + 3) * 128 + e] = a3;
        __syncthreads();
        if (g == 0) {
            float bsum = bb[e] + bb[DIM + e] + bb[2 * DIM + e] + bb[3 * DIM + e];
            #pragma unroll
            for (int m = 0; m < 4; ++m) {
                float v = (part[m * 128 + e] + part[(4 + m) * 128 + e] + bsum) * 0.25f;
                eps[(size_t)(base + m) * DIM + e] = 1.0f / (1.0f + expf(-v));
            }
        }
    }
}

// ================= Phase C: per-pair fused epilogue (one wave per pair) =================
__global__ __launch_bounds__(256) void k_pairs(const int* __restrict__ pairs,
                                               const unsigned long long* __restrict__ mask,
                                               const float* __restrict__ C,
                                               const float* __restrict__ proj,
                                               const float* __restrict__ eps,
                                               const float* __restrict__ x,
                                               const float* __restrict__ salpha_p,
                                               const float* __restrict__ q1p,
                                               const float* __restrict__ q2p,
                                               float* __restrict__ out) {
    int wave = threadIdx.x >> 6;
    int lane = threadIdx.x & 63;
    int p = blockIdx.x * 4 + wave;
    int pm = pairs[p * 2];
    int pn = pairs[p * 2 + 1];

    unsigned long long cw = mask[(size_t)pm * WORDS + lane] & mask[(size_t)pn * WORDS + lane];
    float csum = 0.f;
    int jbase = (lane >> 2) * 256 + (lane & 3);
    while (cw) {
        int bit = __ffsll(cw) - 1;
        csum += C[jbase + bit * 4];
        cw &= cw - 1;
    }

    const float2* Am = (const float2*)(proj + (size_t)pm * DIM);
    const float2* An = (const float2*)(proj + (size_t)pn * DIM);
    const float2* Xm = (const float2*)(x    + (size_t)pm * DIM);
    const float2* Xn = (const float2*)(x    + (size_t)pn * DIM);
    const float2* Em = (const float2*)(eps  + (size_t)pm * DIM);
    const float2* En = (const float2*)(eps  + (size_t)pn * DIM);
    float2 am = Am[lane], an = An[lane];
    float2 xm = Xm[lane], xn = Xn[lane];
    float2 em = Em[lane], en = En[lane];

    float dpx = am.x - an.x, dpy = am.y - an.y;
    float s1 = dpx * dpx + dpy * dpy;
    float dxx = xm.x - xn.x, dxy = xm.y - xn.y;
    float s2 = dxx * dxx + dxy * dxy;
    float s3 = em.x * en.x + em.y * en.y;

    for (int off = 32; off > 0; off >>= 1) {
        s1 += __shfl_xor(s1, off);
        s2 += __shfl_xor(s2, off);
        s3 += __shfl_xor(s3, off);
        csum += __shfl_xor(csum, off);
    }
    if (lane == 0) {
        float lhist  = -sqrtf(s1) + salpha_p[0];
        float ltri   = csum * (-s2);
        float lneigh = s3 * (1.0f / 128.0f);
        float lam = expf(lhist + ltri + lneigh);
        float z = q1p[0] * lam + q2p[0];
        out[p] = 1.0f / (1.0f + expf(-z));
    }
}

extern "C" void kernel_launch(void* const* d_in, const int* in_sizes, int n_in,
                              void* d_out, int out_size, void* d_ws, size_t ws_size,
                              hipStream_t stream) {
    const int*   pairs    = (const int*)d_in[0];
    const int*   adj      = (const int*)d_in[1];
    const int*   nidx     = (const int*)d_in[2];
    const int*   ntype    = (const int*)d_in[3];
    const float* t_events = (const float*)d_in[4];
    const float* x        = (const float*)d_in[5];
    const float* Wp       = (const float*)d_in[6];
    const float* Wb       = (const float*)d_in[7];
    const float* bb       = (const float*)d_in[8];
    const float* theta    = (const float*)d_in[9];
    const float* q1       = (const float*)d_in[10];
    const float* q2       = (const float*)d_in[11];
    float* out = (float*)d_out;

    char* ws = (char*)d_ws;
    unsigned long long* mask = (unsigned long long*)(ws + 0);      // 2 MB
    float* deg    = (float*)(ws + 2097152);                        // 16 KB
    float* C      = (float*)(ws + 2113536);                        // 16 KB
    float* proj   = (float*)(ws + 2129920);                        // 2 MB
    float* eps    = (float*)(ws + 4227072);                        // 2 MB
    float* salpha = (float*)(ws + 6324224);                        // 4 B
    float* h      = (float*)(ws + 6324352);                        // 8 MB
    unsigned short* nbr = (unsigned short*)(ws + 14712960);        // 1.5 MB

    hipLaunchKernelGGL(k_phaseA, dim3(PA_TOTAL),   dim3(256), 0, stream,
                       adj, mask, deg, nbr, x, ntype, Wp, proj, nidx, h, t_events, theta, salpha);
    hipLaunchKernelGGL(k_phaseB, dim3(PB_TOTAL),   dim3(256), 0, stream,
                       mask, deg, nbr, C, h, Wb, bb, eps);
    hipLaunchKernelGGL(k_pairs,  dim3(NPAIRS / 4), dim3(256), 0, stream,
                       pairs, mask, C, proj, eps, x, salpha, q1, q2, out);
}

// Round 9
// 79.101 us; speedup vs baseline: 1.2028x; 1.1036x over previous
//
#include <hip/hip_runtime.h>
#include <math.h>

#define N_NODES 4096
#define DIM     128
#define NPAIRS  32768
#define NEVENTS 4096
#define NTYPES  3
#define NREL    4
#define NNEIGH  16
#define WORDS   64   // 4096 bits / 64
#define MAXDEG  192  // deg ~ Binomial(4096, .02): mean 82, sd 9; P(>192) ~ 0

// Mask word layout (permuted): word w = ch*4+c (ch=chunk of 256 cols, c=component).
// Bit l of word w  <->  column (w>>2)*256 + l*4 + (w&3).

// Phase A block ranges
#define PA_MASK_END  (N_NODES / 4)                  // 1024 blocks: wave per row
#define PA_PROJ_END  (PA_MASK_END + N_NODES / 2)    // 2048 blocks: 2 nodes each
#define PA_HR_END    (PA_PROJ_END + N_NODES * NREL * DIM / 256) // 8192 blocks
#define PA_TOTAL     (PA_HR_END + 1)                // +1 block: sum_alpha

// ================= Phase A: mask+deg+nbrlist | proj | hr | sum_alpha =================
__global__ __launch_bounds__(256) void k_phaseA(const int* __restrict__ adj,
                                                unsigned long long* __restrict__ mask,
                                                float* __restrict__ degf,
                                                unsigned short* __restrict__ nbr,
                                                const float* __restrict__ x,
                                                const int* __restrict__ ntype,
                                                const float* __restrict__ Wp,
                                                float* __restrict__ proj,
                                                const int* __restrict__ nidx,
                                                float* __restrict__ h,
                                                const float* __restrict__ t_events,
                                                const float* __restrict__ theta_p,
                                                float* __restrict__ salpha) {
    __shared__ float smem[512];   // 2 KB, reused per branch
    int b = blockIdx.x;

    if (b < PA_MASK_END) {
        // ---- adjacency: wave per row; each lane ends owning word `lane` ----
        int wave = threadIdx.x >> 6;
        int lane = threadIdx.x & 63;
        int row  = b * 4 + wave;
        const int4* arow = (const int4*)(adj + (size_t)row * N_NODES);
        unsigned long long myw = 0ULL;
        #pragma unroll
        for (int ch = 0; ch < 16; ++ch) {
            int4 v = arow[ch * 64 + lane];
            unsigned long long b0 = __ballot(v.x != 0);
            unsigned long long b1 = __ballot(v.y != 0);
            unsigned long long b2 = __ballot(v.z != 0);
            unsigned long long b3 = __ballot(v.w != 0);
            if ((lane >> 2) == ch) {
                int c = lane & 3;
                myw = (c == 0) ? b0 : (c == 1) ? b1 : (c == 2) ? b2 : b3;
            }
        }
        mask[(size_t)row * WORDS + lane] = myw;
        // prefix-scan popcounts -> compaction offsets
        int pc = (int)__popcll(myw);
        int scan = pc;
        #pragma unroll
        for (int off = 1; off < 64; off <<= 1) {
            int nv = __shfl_up(scan, off);
            if (lane >= off) scan += nv;
        }
        int excl = scan - pc;
        if (lane == 63) degf[row] = (float)scan;
        unsigned short* nl = nbr + (size_t)row * MAXDEG;
        int jb = (lane >> 2) * 256 + (lane & 3);
        unsigned long long ww = myw;
        int o = excl;
        while (ww) {
            int bit = __ffsll(ww) - 1;
            nl[o++] = (unsigned short)(jb + bit * 4);
            ww &= ww - 1;
        }

    } else if (b < PA_PROJ_END) {
        // ---- proj[n] = x[n] @ W_proj[type[n]], 2 nodes per block ----
        int base = (b - PA_MASK_END) * 2;
        int g = threadIdx.x >> 7;
        int e = threadIdx.x & 127;
        int n = base + g;
        float* xs = smem;  // [2][128]
        xs[g * DIM + e] = x[(size_t)n * DIM + e];
        __syncthreads();
        int t = ntype[n];
        const float* W = Wp + (size_t)t * DIM * DIM + e;
        float acc = 0.f;
        #pragma unroll 8
        for (int d = 0; d < DIM; ++d)
            acc += xs[g * DIM + d] * W[(size_t)d * DIM];
        proj[(size_t)n * DIM + e] = acc;

    } else if (b < PA_HR_END) {
        // ---- h[n][r][d] = mean_k x[nidx[n][r][k]][d] ----
        int tid = (b - PA_PROJ_END) * 256 + threadIdx.x;
        int d  = tid & (DIM - 1);
        int nr = tid >> 7;
        const int4* idx4 = (const int4*)(nidx + (size_t)nr * NNEIGH);
        int4 i0 = idx4[0], i1 = idx4[1], i2 = idx4[2], i3 = idx4[3];
        float s = 0.f;
        s += x[(size_t)i0.x * DIM + d]; s += x[(size_t)i0.y * DIM + d];
        s += x[(size_t)i0.z * DIM + d]; s += x[(size_t)i0.w * DIM + d];
        s += x[(size_t)i1.x * DIM + d]; s += x[(size_t)i1.y * DIM + d];
        s += x[(size_t)i1.z * DIM + d]; s += x[(size_t)i1.w * DIM + d];
        s += x[(size_t)i2.x * DIM + d]; s += x[(size_t)i2.y * DIM + d];
        s += x[(size_t)i2.z * DIM + d]; s += x[(size_t)i2.w * DIM + d];
        s += x[(size_t)i3.x * DIM + d]; s += x[(size_t)i3.y * DIM + d];
        s += x[(size_t)i3.z * DIM + d]; s += x[(size_t)i3.w * DIM + d];
        h[tid] = s * (1.0f / 16.0f);

    } else {
        // ---- sum_alpha ----
        float th = theta_p[0];
        float acc = 0.f;
        for (int i = threadIdx.x; i < NEVENTS; i += 256)
            acc += expf(-th * (1.0f - t_events[i]));
        smem[threadIdx.x] = acc;
        __syncthreads();
        for (int s = 128; s > 0; s >>= 1) {
            if (threadIdx.x < s) smem[threadIdx.x] += smem[threadIdx.x + s];
            __syncthreads();
        }
        if (threadIdx.x == 0) salpha[0] = smem[0];
    }
}

// ================= K_clust: block per node; wave w takes neighbors it = w + 4t =================
__global__ __launch_bounds__(256) void k_clust(const unsigned long long* __restrict__ mask,
                                               const float* __restrict__ degf,
                                               const unsigned short* __restrict__ nbr,
                                               float* __restrict__ C) {
    __shared__ unsigned int wacc[4];
    int node = blockIdx.x;
    int wave = threadIdx.x >> 6;
    int lane = threadIdx.x & 63;
    unsigned long long my = mask[(size_t)node * WORDS + lane];
    int dg = (int)degf[node];
    const unsigned short* nlist = nbr + (size_t)node * MAXDEG;
    int pidx = wave + 4 * lane;
    int pre = (lane < 48) ? (int)nlist[pidx] : 0;
    int nit = (dg - wave + 3) >> 2;
    if (nit < 0) nit = 0;
    unsigned int acc = 0;
    #pragma unroll 4
    for (int t = 0; t < nit; ++t) {
        int j = __shfl(pre, t);
        acc += __popcll(my & mask[(size_t)j * WORDS + lane]);
    }
    for (int off = 32; off > 0; off >>= 1) acc += __shfl_xor(acc, off);
    if (lane == 0) wacc[wave] = acc;
    __syncthreads();
    if (threadIdx.x == 0) {
        float tri = (float)(wacc[0] + wacc[1] + wacc[2] + wacc[3]);
        float dgF = (float)dg;
        float denom = dgF * (dgF - 1.0f);
        if (denom == 0.0f) denom = 1e-6f;
        C[node] = 2.0f * tri / denom;
    }
}

// ================= K_eps: H[4096x512] @ Wcat[512x128] with 2-axis register blocking =================
// 1024 blocks, 4 nodes/block. 256 threads = 32 e-groups (4 e) x 8 k-eighths (64 k).
__global__ __launch_bounds__(256) void k_eps(const float* __restrict__ h,
                                             const float* __restrict__ Wb,
                                             const float* __restrict__ bb,
                                             float* __restrict__ eps) {
    __shared__ float hs[4 * 512];        // 8 KB
    __shared__ float part[8 * 4 * 128];  // 16 KB
    int base = blockIdx.x * 4;
    int eg = threadIdx.x & 31;           // e-group
    int g  = threadIdx.x >> 5;           // k-eighth
    int e0 = eg * 4;

    const float4* hsrc = (const float4*)(h + (size_t)base * NREL * DIM);
    float4* hs4 = (float4*)hs;
    hs4[threadIdx.x]       = hsrc[threadIdx.x];
    hs4[threadIdx.x + 256] = hsrc[threadIdx.x + 256];
    __syncthreads();

    const float* W = Wb + (size_t)(g * 64) * DIM + e0;
    float4 a0 = {0,0,0,0}, a1 = {0,0,0,0}, a2 = {0,0,0,0}, a3 = {0,0,0,0};
    int hq = g * 16;  // float4 index base within a node's 128 float4s
    #pragma unroll 2
    for (int kk = 0; kk < 16; ++kk) {
        float4 h0 = hs4[0 * 128 + hq + kk];
        float4 h1 = hs4[1 * 128 + hq + kk];
        float4 h2 = hs4[2 * 128 + hq + kk];
        float4 h3 = hs4[3 * 128 + hq + kk];
        float4 w0 = *(const float4*)&W[(size_t)(kk * 4 + 0) * DIM];
        float4 w1 = *(const float4*)&W[(size_t)(kk * 4 + 1) * DIM];
        float4 w2 = *(const float4*)&W[(size_t)(kk * 4 + 2) * DIM];
        float4 w3 = *(const float4*)&W[(size_t)(kk * 4 + 3) * DIM];
        a0.x += h0.x*w0.x + h0.y*w1.x + h0.z*w2.x + h0.w*w3.x;
        a0.y += h0.x*w0.y + h0.y*w1.y + h0.z*w2.y + h0.w*w3.y;
        a0.z += h0.x*w0.z + h0.y*w1.z + h0.z*w2.z + h0.w*w3.z;
        a0.w += h0.x*w0.w + h0.y*w1.w + h0.z*w2.w + h0.w*w3.w;
        a1.x += h1.x*w0.x + h1.y*w1.x + h1.z*w2.x + h1.w*w3.x;
        a1.y += h1.x*w0.y + h1.y*w1.y + h1.z*w2.y + h1.w*w3.y;
        a1.z += h1.x*w0.z + h1.y*w1.z + h1.z*w2.z + h1.w*w3.z;
        a1.w += h1.x*w0.w + h1.y*w1.w + h1.z*w2.w + h1.w*w3.w;
        a2.x += h2.x*w0.x + h2.y*w1.x + h2.z*w2.x + h2.w*w3.x;
        a2.y += h2.x*w0.y + h2.y*w1.y + h2.z*w2.y + h2.w*w3.y;
        a2.z += h2.x*w0.z + h2.y*w1.z + h2.z*w2.z + h2.w*w3.z;
        a2.w += h2.x*w0.w + h2.y*w1.w + h2.z*w2.w + h2.w*w3.w;
        a3.x += h3.x*w0.x + h3.y*w1.x + h3.z*w2.x + h3.w*w3.x;
        a3.y += h3.x*w0.y + h3.y*w1.y + h3.z*w2.y + h3.w*w3.y;
        a3.z += h3.x*w0.z + h3.y*w1.z + h3.z*w2.z + h3.w*w3.z;
        a3.w += h3.x*w0.w + h3.y*w1.w + h3.z*w2.w + h3.w*w3.w;
    }
    float4* p4 = (float4*)part;
    // part[g][m][e0..e0+3]
    p4[(g * 4 + 0) * 32 + eg] = a0;
    p4[(g * 4 + 1) * 32 + eg] = a1;
    p4[(g * 4 + 2) * 32 + eg] = a2;
    p4[(g * 4 + 3) * 32 + eg] = a3;
    __syncthreads();
    #pragma unroll
    for (int rep = 0; rep < 2; ++rep) {
        int idx = threadIdx.x + rep * 256;   // (node, e)
        int m = idx >> 7;
        int e = idx & 127;
        float s = 0.f;
        #pragma unroll
        for (int gg = 0; gg < 8; ++gg)
            s += part[(gg * 4 + m) * 128 + e];
        float bsum = bb[e] + bb[DIM + e] + bb[2 * DIM + e] + bb[3 * DIM + e];
        float v = (s + bsum) * 0.25f;
        eps[(size_t)(base + m) * DIM + e] = 1.0f / (1.0f + expf(-v));
    }
}

// ================= Phase C: per-pair fused epilogue (one wave per pair) =================
__global__ __launch_bounds__(256) void k_pairs(const int* __restrict__ pairs,
                                               const unsigned long long* __restrict__ mask,
                                               const float* __restrict__ C,
                                               const float* __restrict__ proj,
                                               const float* __restrict__ eps,
                                               const float* __restrict__ x,
                                               const float* __restrict__ salpha_p,
                                               const float* __restrict__ q1p,
                                               const float* __restrict__ q2p,
                                               float* __restrict__ out) {
    int wave = threadIdx.x >> 6;
    int lane = threadIdx.x & 63;
    int p = blockIdx.x * 4 + wave;
    int pm = pairs[p * 2];
    int pn = pairs[p * 2 + 1];

    unsigned long long cw = mask[(size_t)pm * WORDS + lane] & mask[(size_t)pn * WORDS + lane];
    float csum = 0.f;
    int jbase = (lane >> 2) * 256 + (lane & 3);
    while (cw) {
        int bit = __ffsll(cw) - 1;
        csum += C[jbase + bit * 4];
        cw &= cw - 1;
    }

    const float2* Am = (const float2*)(proj + (size_t)pm * DIM);
    const float2* An = (const float2*)(proj + (size_t)pn * DIM);
    const float2* Xm = (const float2*)(x    + (size_t)pm * DIM);
    const float2* Xn = (const float2*)(x    + (size_t)pn * DIM);
    const float2* Em = (const float2*)(eps  + (size_t)pm * DIM);
    const float2* En = (const float2*)(eps  + (size_t)pn * DIM);
    float2 am = Am[lane], an = An[lane];
    float2 xm = Xm[lane], xn = Xn[lane];
    float2 em = Em[lane], en = En[lane];

    float dpx = am.x - an.x, dpy = am.y - an.y;
    float s1 = dpx * dpx + dpy * dpy;
    float dxx = xm.x - xn.x, dxy = xm.y - xn.y;
    float s2 = dxx * dxx + dxy * dxy;
    float s3 = em.x * en.x + em.y * en.y;

    for (int off = 32; off > 0; off >>= 1) {
        s1 += __shfl_xor(s1, off);
        s2 += __shfl_xor(s2, off);
        s3 += __shfl_xor(s3, off);
        csum += __shfl_xor(csum, off);
    }
    if (lane == 0) {
        float lhist  = -sqrtf(s1) + salpha_p[0];
        float ltri   = csum * (-s2);
        float lneigh = s3 * (1.0f / 128.0f);
        float lam = expf(lhist + ltri + lneigh);
        float z = q1p[0] * lam + q2p[0];
        out[p] = 1.0f / (1.0f + expf(-z));
    }
}

extern "C" void kernel_launch(void* const* d_in, const int* in_sizes, int n_in,
                              void* d_out, int out_size, void* d_ws, size_t ws_size,
                              hipStream_t stream) {
    const int*   pairs    = (const int*)d_in[0];
    const int*   adj      = (const int*)d_in[1];
    const int*   nidx     = (const int*)d_in[2];
    const int*   ntype    = (const int*)d_in[3];
    const float* t_events = (const float*)d_in[4];
    const float* x        = (const float*)d_in[5];
    const float* Wp       = (const float*)d_in[6];
    const float* Wb       = (const float*)d_in[7];
    const float* bb       = (const float*)d_in[8];
    const float* theta    = (const float*)d_in[9];
    const float* q1       = (const float*)d_in[10];
    const float* q2       = (const float*)d_in[11];
    float* out = (float*)d_out;

    char* ws = (char*)d_ws;
    unsigned long long* mask = (unsigned long long*)(ws + 0);      // 2 MB
    float* deg    = (float*)(ws + 2097152);                        // 16 KB
    float* C      = (float*)(ws + 2113536);                        // 16 KB
    float* proj   = (float*)(ws + 2129920);                        // 2 MB
    float* eps    = (float*)(ws + 4227072);                        // 2 MB
    float* salpha = (float*)(ws + 6324224);                        // 4 B
    float* h      = (float*)(ws + 6324352);                        // 8 MB
    unsigned short* nbr = (unsigned short*)(ws + 14712960);        // 1.5 MB

    hipLaunchKernelGGL(k_phaseA, dim3(PA_TOTAL),    dim3(256), 0, stream,
                       adj, mask, deg, nbr, x, ntype, Wp, proj, nidx, h, t_events, theta, salpha);
    hipLaunchKernelGGL(k_clust,  dim3(N_NODES),     dim3(256), 0, stream, mask, deg, nbr, C);
    hipLaunchKernelGGL(k_eps,    dim3(N_NODES / 4), dim3(256), 0, stream, h, Wb, bb, eps);
    hipLaunchKernelGGL(k_pairs,  dim3(NPAIRS / 4),  dim3(256), 0, stream,
                       pairs, mask, C, proj, eps, x, salpha, q1, q2, out);
}

// Round 10
// 77.394 us; speedup vs baseline: 1.2293x; 1.0221x over previous
//
#include <hip/hip_runtime.h>
#include <math.h>

#define N_NODES 4096
#define DIM     128
#define NPAIRS  32768
#define NEVENTS 4096
#define NTYPES  3
#define NREL    4
#define NNEIGH  16
#define WORDS   64   // 4096 bits / 64
#define MAXDEG  192  // deg ~ Binomial(4096, .02): mean 82, sd 9; P(>192) ~ 0

// Mask word layout (permuted): word w = ch*4+c (ch=chunk of 256 cols, c=component).
// Bit l of word w  <->  column (w>>2)*256 + l*4 + (w&3).

// Phase A block ranges
#define PA_MASK_END  (N_NODES / 4)                  // 1024 blocks: wave per row
#define PA_PROJ_END  (PA_MASK_END + N_NODES)        // 4096 blocks: 1 node each
#define PA_HR_END    (PA_PROJ_END + N_NODES * NREL * DIM / (256 * 4)) // 2048 blocks
#define PA_TOTAL     (PA_HR_END + 1)                // +1 block: sum_alpha

// ================= Phase A: mask+deg+nbrlist | proj | hr | sum_alpha =================
__global__ __launch_bounds__(256) void k_phaseA(const int* __restrict__ adj,
                                                unsigned long long* __restrict__ mask,
                                                float* __restrict__ degf,
                                                unsigned short* __restrict__ nbr,
                                                const float* __restrict__ x,
                                                const int* __restrict__ ntype,
                                                const float* __restrict__ Wp,
                                                float* __restrict__ proj,
                                                const int* __restrict__ nidx,
                                                float* __restrict__ h,
                                                const float* __restrict__ t_events,
                                                const float* __restrict__ theta_p,
                                                float* __restrict__ salpha) {
    __shared__ float smem[1280];   // 5 KB: proj xs[128]+part[8][128]; others use less
    int b = blockIdx.x;

    if (b < PA_MASK_END) {
        // ---- adjacency: wave per row; each lane ends owning word `lane` ----
        int wave = threadIdx.x >> 6;
        int lane = threadIdx.x & 63;
        int row  = b * 4 + wave;
        const int4* arow = (const int4*)(adj + (size_t)row * N_NODES);
        unsigned long long myw = 0ULL;
        #pragma unroll
        for (int ch = 0; ch < 16; ++ch) {
            int4 v = arow[ch * 64 + lane];
            unsigned long long b0 = __ballot(v.x != 0);
            unsigned long long b1 = __ballot(v.y != 0);
            unsigned long long b2 = __ballot(v.z != 0);
            unsigned long long b3 = __ballot(v.w != 0);
            if ((lane >> 2) == ch) {
                int c = lane & 3;
                myw = (c == 0) ? b0 : (c == 1) ? b1 : (c == 2) ? b2 : b3;
            }
        }
        mask[(size_t)row * WORDS + lane] = myw;
        // prefix-scan popcounts -> compaction offsets
        int pc = (int)__popcll(myw);
        int scan = pc;
        #pragma unroll
        for (int off = 1; off < 64; off <<= 1) {
            int nv = __shfl_up(scan, off);
            if (lane >= off) scan += nv;
        }
        int excl = scan - pc;
        if (lane == 63) degf[row] = (float)scan;
        unsigned short* nl = nbr + (size_t)row * MAXDEG;
        int jb = (lane >> 2) * 256 + (lane & 3);
        unsigned long long ww = myw;
        int o = excl;
        while (ww) {
            int bit = __ffsll(ww) - 1;
            nl[o++] = (unsigned short)(jb + bit * 4);
            ww &= ww - 1;
        }

    } else if (b < PA_PROJ_END) {
        // ---- proj[n] = x[n] @ W_proj[type[n]]; 1 node/block, 32 eg x 8 kg ----
        int n = b - PA_MASK_END;
        int eg = threadIdx.x & 31;
        int kg = threadIdx.x >> 5;
        float* xs = smem;          // [128]
        float* part = smem + 128;  // [8][128]
        if (threadIdx.x < 32)
            ((float4*)xs)[threadIdx.x] = ((const float4*)(x + (size_t)n * DIM))[threadIdx.x];
        __syncthreads();
        int t = ntype[n];
        const float4* W4 = (const float4*)(Wp + (size_t)t * DIM * DIM) + eg;
        float4 acc = {0.f, 0.f, 0.f, 0.f};
        int k0 = kg * 16;
        #pragma unroll
        for (int kk = 0; kk < 16; ++kk) {
            float xk = xs[k0 + kk];
            float4 w = W4[(size_t)(k0 + kk) * 32];
            acc.x += xk * w.x; acc.y += xk * w.y; acc.z += xk * w.z; acc.w += xk * w.w;
        }
        ((float4*)(part + kg * 128))[eg] = acc;
        __syncthreads();
        if (threadIdx.x < 128) {
            int e = threadIdx.x;
            float s = part[e] + part[128 + e] + part[256 + e] + part[384 + e]
                    + part[512 + e] + part[640 + e] + part[768 + e] + part[896 + e];
            proj[(size_t)n * DIM + e] = s;
        }

    } else if (b < PA_HR_END) {
        // ---- h[n][r][dq*4..+3] = mean_k x[nidx[n][r][k]][...]; thread per (nr, d-quad) ----
        int tid = (b - PA_PROJ_END) * 256 + threadIdx.x;   // 524288 total
        int dq = tid & 31;
        int nr = tid >> 5;
        const int4* idx4 = (const int4*)(nidx + (size_t)nr * NNEIGH);
        int4 i0 = idx4[0], i1 = idx4[1], i2 = idx4[2], i3 = idx4[3];
        const float4* xb = (const float4*)x;
        float4 s = {0.f, 0.f, 0.f, 0.f};
        float4 v;
        #define ACC4(i) v = xb[(size_t)(i) * 32 + dq]; s.x += v.x; s.y += v.y; s.z += v.z; s.w += v.w;
        ACC4(i0.x) ACC4(i0.y) ACC4(i0.z) ACC4(i0.w)
        ACC4(i1.x) ACC4(i1.y) ACC4(i1.z) ACC4(i1.w)
        ACC4(i2.x) ACC4(i2.y) ACC4(i2.z) ACC4(i2.w)
        ACC4(i3.x) ACC4(i3.y) ACC4(i3.z) ACC4(i3.w)
        #undef ACC4
        float4 r;
        r.x = s.x * (1.0f / 16.0f); r.y = s.y * (1.0f / 16.0f);
        r.z = s.z * (1.0f / 16.0f); r.w = s.w * (1.0f / 16.0f);
        ((float4*)h)[(size_t)nr * 32 + dq] = r;

    } else {
        // ---- sum_alpha ----
        float th = theta_p[0];
        float acc = 0.f;
        for (int i = threadIdx.x; i < NEVENTS; i += 256)
            acc += expf(-th * (1.0f - t_events[i]));
        smem[threadIdx.x] = acc;
        __syncthreads();
        for (int s = 128; s > 0; s >>= 1) {
            if (threadIdx.x < s) smem[threadIdx.x] += smem[threadIdx.x + s];
            __syncthreads();
        }
        if (threadIdx.x == 0) salpha[0] = smem[0];
    }
}

// ================= K_clust: block per node; wave w takes neighbors it = w + 4t =================
__global__ __launch_bounds__(256) void k_clust(const unsigned long long* __restrict__ mask,
                                               const float* __restrict__ degf,
                                               const unsigned short* __restrict__ nbr,
                                               float* __restrict__ C) {
    __shared__ unsigned int wacc[4];
    int node = blockIdx.x;
    int wave = threadIdx.x >> 6;
    int lane = threadIdx.x & 63;
    unsigned long long my = mask[(size_t)node * WORDS + lane];
    int dg = (int)degf[node];
    const unsigned short* nlist = nbr + (size_t)node * MAXDEG;
    int pidx = wave + 4 * lane;
    int pre = (lane < 48) ? (int)nlist[pidx] : 0;
    int nit = (dg - wave + 3) >> 2;
    if (nit < 0) nit = 0;
    unsigned int acc = 0;
    #pragma unroll 4
    for (int t = 0; t < nit; ++t) {
        int j = __shfl(pre, t);
        acc += __popcll(my & mask[(size_t)j * WORDS + lane]);
    }
    for (int off = 32; off > 0; off >>= 1) acc += __shfl_xor(acc, off);
    if (lane == 0) wacc[wave] = acc;
    __syncthreads();
    if (threadIdx.x == 0) {
        float tri = (float)(wacc[0] + wacc[1] + wacc[2] + wacc[3]);
        float dgF = (float)dg;
        float denom = dgF * (dgF - 1.0f);
        if (denom == 0.0f) denom = 1e-6f;
        C[node] = 2.0f * tri / denom;
    }
}

// ================= K_eps: H[4096x512] @ Wcat[512x128] with 2-axis register blocking =================
__global__ __launch_bounds__(256) void k_eps(const float* __restrict__ h,
                                             const float* __restrict__ Wb,
                                             const float* __restrict__ bb,
                                             float* __restrict__ eps) {
    __shared__ float hs[4 * 512];        // 8 KB
    __shared__ float part[8 * 4 * 128];  // 16 KB
    int base = blockIdx.x * 4;
    int eg = threadIdx.x & 31;           // e-group
    int g  = threadIdx.x >> 5;           // k-eighth
    int e0 = eg * 4;

    const float4* hsrc = (const float4*)(h + (size_t)base * NREL * DIM);
    float4* hs4 = (float4*)hs;
    hs4[threadIdx.x]       = hsrc[threadIdx.x];
    hs4[threadIdx.x + 256] = hsrc[threadIdx.x + 256];
    __syncthreads();

    const float* W = Wb + (size_t)(g * 64) * DIM + e0;
    float4 a0 = {0,0,0,0}, a1 = {0,0,0,0}, a2 = {0,0,0,0}, a3 = {0,0,0,0};
    int hq = g * 16;  // float4 index base within a node's 128 float4s
    #pragma unroll 2
    for (int kk = 0; kk < 16; ++kk) {
        float4 h0 = hs4[0 * 128 + hq + kk];
        float4 h1 = hs4[1 * 128 + hq + kk];
        float4 h2 = hs4[2 * 128 + hq + kk];
        float4 h3 = hs4[3 * 128 + hq + kk];
        float4 w0 = *(const float4*)&W[(size_t)(kk * 4 + 0) * DIM];
        float4 w1 = *(const float4*)&W[(size_t)(kk * 4 + 1) * DIM];
        float4 w2 = *(const float4*)&W[(size_t)(kk * 4 + 2) * DIM];
        float4 w3 = *(const float4*)&W[(size_t)(kk * 4 + 3) * DIM];
        a0.x += h0.x*w0.x + h0.y*w1.x + h0.z*w2.x + h0.w*w3.x;
        a0.y += h0.x*w0.y + h0.y*w1.y + h0.z*w2.y + h0.w*w3.y;
        a0.z += h0.x*w0.z + h0.y*w1.z + h0.z*w2.z + h0.w*w3.z;
        a0.w += h0.x*w0.w + h0.y*w1.w + h0.z*w2.w + h0.w*w3.w;
        a1.x += h1.x*w0.x + h1.y*w1.x + h1.z*w2.x + h1.w*w3.x;
        a1.y += h1.x*w0.y + h1.y*w1.y + h1.z*w2.y + h1.w*w3.y;
        a1.z += h1.x*w0.z + h1.y*w1.z + h1.z*w2.z + h1.w*w3.z;
        a1.w += h1.x*w0.w + h1.y*w1.w + h1.z*w2.w + h1.w*w3.w;
        a2.x += h2.x*w0.x + h2.y*w1.x + h2.z*w2.x + h2.w*w3.x;
        a2.y += h2.x*w0.y + h2.y*w1.y + h2.z*w2.y + h2.w*w3.y;
        a2.z += h2.x*w0.z + h2.y*w1.z + h2.z*w2.z + h2.w*w3.z;
        a2.w += h2.x*w0.w + h2.y*w1.w + h2.z*w2.w + h2.w*w3.w;
        a3.x += h3.x*w0.x + h3.y*w1.x + h3.z*w2.x + h3.w*w3.x;
        a3.y += h3.x*w0.y + h3.y*w1.y + h3.z*w2.y + h3.w*w3.y;
        a3.z += h3.x*w0.z + h3.y*w1.z + h3.z*w2.z + h3.w*w3.z;
        a3.w += h3.x*w0.w + h3.y*w1.w + h3.z*w2.w + h3.w*w3.w;
    }
    float4* p4 = (float4*)part;
    p4[(g * 4 + 0) * 32 + eg] = a0;
    p4[(g * 4 + 1) * 32 + eg] = a1;
    p4[(g * 4 + 2) * 32 + eg] = a2;
    p4[(g * 4 + 3) * 32 + eg] = a3;
    __syncthreads();
    #pragma unroll
    for (int rep = 0; rep < 2; ++rep) {
        int idx = threadIdx.x + rep * 256;   // (node, e)
        int m = idx >> 7;
        int e = idx & 127;
        float s = 0.f;
        #pragma unroll
        for (int gg = 0; gg < 8; ++gg)
            s += part[(gg * 4 + m) * 128 + e];
        float bsum = bb[e] + bb[DIM + e] + bb[2 * DIM + e] + bb[3 * DIM + e];
        float v = (s + bsum) * 0.25f;
        eps[(size_t)(base + m) * DIM + e] = 1.0f / (1.0f + expf(-v));
    }
}

// ================= Phase C: per-pair fused epilogue (one wave per pair) =================
__global__ __launch_bounds__(256) void k_pairs(const int* __restrict__ pairs,
                                               const unsigned long long* __restrict__ mask,
                                               const float* __restrict__ C,
                                               const float* __restrict__ proj,
                                               const float* __restrict__ eps,
                                               const float* __restrict__ x,
                                               const float* __restrict__ salpha_p,
                                               const float* __restrict__ q1p,
                                               const float* __restrict__ q2p,
                                               float* __restrict__ out) {
    int wave = threadIdx.x >> 6;
    int lane = threadIdx.x & 63;
    int p = blockIdx.x * 4 + wave;
    int pm = pairs[p * 2];
    int pn = pairs[p * 2 + 1];

    unsigned long long cw = mask[(size_t)pm * WORDS + lane] & mask[(size_t)pn * WORDS + lane];
    float csum = 0.f;
    int jbase = (lane >> 2) * 256 + (lane & 3);
    while (cw) {
        int bit = __ffsll(cw) - 1;
        csum += C[jbase + bit * 4];
        cw &= cw - 1;
    }

    const float2* Am = (const float2*)(proj + (size_t)pm * DIM);
    const float2* An = (const float2*)(proj + (size_t)pn * DIM);
    const float2* Xm = (const float2*)(x    + (size_t)pm * DIM);
    const float2* Xn = (const float2*)(x    + (size_t)pn * DIM);
    const float2* Em = (const float2*)(eps  + (size_t)pm * DIM);
    const float2* En = (const float2*)(eps  + (size_t)pn * DIM);
    float2 am = Am[lane], an = An[lane];
    float2 xm = Xm[lane], xn = Xn[lane];
    float2 em = Em[lane], en = En[lane];

    float dpx = am.x - an.x, dpy = am.y - an.y;
    float s1 = dpx * dpx + dpy * dpy;
    float dxx = xm.x - xn.x, dxy = xm.y - xn.y;
    float s2 = dxx * dxx + dxy * dxy;
    float s3 = em.x * en.x + em.y * en.y;

    for (int off = 32; off > 0; off >>= 1) {
        s1 += __shfl_xor(s1, off);
        s2 += __shfl_xor(s2, off);
        s3 += __shfl_xor(s3, off);
        csum += __shfl_xor(csum, off);
    }
    if (lane == 0) {
        float lhist  = -sqrtf(s1) + salpha_p[0];
        float ltri   = csum * (-s2);
        float lneigh = s3 * (1.0f / 128.0f);
        float lam = expf(lhist + ltri + lneigh);
        float z = q1p[0] * lam + q2p[0];
        out[p] = 1.0f / (1.0f + expf(-z));
    }
}

extern "C" void kernel_launch(void* const* d_in, const int* in_sizes, int n_in,
                              void* d_out, int out_size, void* d_ws, size_t ws_size,
                              hipStream_t stream) {
    const int*   pairs    = (const int*)d_in[0];
    const int*   adj      = (const int*)d_in[1];
    const int*   nidx     = (const int*)d_in[2];
    const int*   ntype    = (const int*)d_in[3];
    const float* t_events = (const float*)d_in[4];
    const float* x        = (const float*)d_in[5];
    const float* Wp       = (const float*)d_in[6];
    const float* Wb       = (const float*)d_in[7];
    const float* bb       = (const float*)d_in[8];
    const float* theta    = (const float*)d_in[9];
    const float* q1       = (const float*)d_in[10];
    const float* q2       = (const float*)d_in[11];
    float* out = (float*)d_out;

    char* ws = (char*)d_ws;
    unsigned long long* mask = (unsigned long long*)(ws + 0);      // 2 MB
    float* deg    = (float*)(ws + 2097152);                        // 16 KB
    float* C      = (float*)(ws + 2113536);                        // 16 KB
    float* proj   = (float*)(ws + 2129920);                        // 2 MB
    float* eps    = (float*)(ws + 4227072);                        // 2 MB
    float* salpha = (float*)(ws + 6324224);                        // 4 B
    float* h      = (float*)(ws + 6324352);                        // 8 MB
    unsigned short* nbr = (unsigned short*)(ws + 14712960);        // 1.5 MB

    hipLaunchKernelGGL(k_phaseA, dim3(PA_TOTAL),    dim3(256), 0, stream,
                       adj, mask, deg, nbr, x, ntype, Wp, proj, nidx, h, t_events, theta, salpha);
    hipLaunchKernelGGL(k_clust,  dim3(N_NODES),     dim3(256), 0, stream, mask, deg, nbr, C);
    hipLaunchKernelGGL(k_eps,    dim3(N_NODES / 4), dim3(256), 0, stream, h, Wb, bb, eps);
    hipLaunchKernelGGL(k_pairs,  dim3(NPAIRS / 4),  dim3(256), 0, stream,
                       pairs, mask, C, proj, eps, x, salpha, q1, q2, out);
}